// Round 1
// baseline (677.970 us; speedup 1.0000x reference)
//
#include <hip/hip_runtime.h>
#include <hip/hip_bf16.h>

// GAT classifier: 2x GATConv + global_mean_pool + linear.
// N=50000 nodes, E=800000 edges, IN=128, HID=64, HEADS=4, CLASSES=16, GRAPHS=64.
// Strategy: CSR-by-dst (built per launch), one wave per dst node for aggregation
// (no scatter atomics), softmax max-shift skipped (shift-invariant, no overflow).

#define Nn 50000
#define Ed 800000
#define NEG 0.2f

__device__ __forceinline__ float lrelu(float x){ return x > 0.f ? x : NEG*x; }

// ---------------- CSR build ----------------
__global__ void k_degree(const int* __restrict__ dst, int* __restrict__ deg){
    int e = blockIdx.x*256 + threadIdx.x;
    if (e < Ed) atomicAdd(&deg[dst[e]], 1);
}

__global__ void k_scan(const int* __restrict__ deg, int* __restrict__ rowptr, int* __restrict__ cursor){
    __shared__ int sums[1024];
    int tid = threadIdx.x;
    const int CH = (Nn + 1023)/1024; // 49
    int start = tid*CH;
    int s = 0;
    for (int i = 0; i < CH; i++){ int idx = start+i; if (idx < Nn) s += deg[idx]; }
    sums[tid] = s; __syncthreads();
    for (int off = 1; off < 1024; off <<= 1){
        int v = (tid >= off) ? sums[tid-off] : 0;
        __syncthreads();
        sums[tid] += v;
        __syncthreads();
    }
    int run = sums[tid] - s; // exclusive
    for (int i = 0; i < CH; i++){
        int idx = start+i;
        if (idx < Nn){ rowptr[idx] = run; cursor[idx] = run; run += deg[idx]; }
    }
    if (tid == 1023) rowptr[Nn] = sums[1023];
}

__global__ void k_scatter(const int* __restrict__ src, const int* __restrict__ dst,
                          int* __restrict__ cursor, int* __restrict__ csr){
    int e = blockIdx.x*256 + threadIdx.x;
    if (e < Ed){
        int pos = atomicAdd(&cursor[dst[e]], 1);
        csr[pos] = src[e];
    }
}

// ---------------- fp32 GEMM: C[Nn,NC] = A[Nn,K] @ B[K,NC], tile 64x64, K-chunk 64 --------
template<int K, int NC>
__global__ __launch_bounds__(256) void k_gemm(const float* __restrict__ A, const float* __restrict__ B,
                                              float* __restrict__ C){
    __shared__ float As[64][68];
    __shared__ float Bs[64][64];
    const int tid = threadIdx.x;
    const int row0 = blockIdx.x*64;
    const int col0 = blockIdx.y*64;
    const int tx = tid & 15, ty = tid >> 4;
    float acc[4][4] = {};
    for (int kc = 0; kc < K; kc += 64){
        for (int g = tid; g < 1024; g += 256){
            int r = g >> 4, c4 = (g & 15) << 2;
            int row = row0 + r;
            float4 av = make_float4(0.f,0.f,0.f,0.f);
            if (row < Nn) av = *(const float4*)&A[(size_t)row*K + kc + c4];
            *(float4*)&As[r][c4] = av;
            *(float4*)&Bs[r][c4] = *(const float4*)&B[(size_t)(kc + r)*NC + col0 + c4];
        }
        __syncthreads();
        #pragma unroll
        for (int k = 0; k < 64; k += 4){
            float a_[4][4];
            #pragma unroll
            for (int i = 0; i < 4; i++){
                float4 t = *(const float4*)&As[ty*4+i][k];
                a_[i][0]=t.x; a_[i][1]=t.y; a_[i][2]=t.z; a_[i][3]=t.w;
            }
            #pragma unroll
            for (int kk = 0; kk < 4; kk++){
                float4 b = *(const float4*)&Bs[k+kk][tx*4];
                float bb[4] = {b.x, b.y, b.z, b.w};
                #pragma unroll
                for (int i = 0; i < 4; i++)
                    #pragma unroll
                    for (int j = 0; j < 4; j++)
                        acc[i][j] += a_[i][kk]*bb[j];
            }
        }
        __syncthreads();
    }
    #pragma unroll
    for (int i = 0; i < 4; i++){
        int row = row0 + ty*4 + i;
        if (row < Nn){
            float4 o = make_float4(acc[i][0], acc[i][1], acc[i][2], acc[i][3]);
            *(float4*)&C[(size_t)row*NC + col0 + tx*4] = o;
        }
    }
}

// ---------------- attention coefficients ----------------
// layer 1: asrc[n,h] = sum_d h1[n,h*64+d]*a_src[h,d]; one wave per node
__global__ __launch_bounds__(256) void k_att1(const float* __restrict__ h1,
                                              const float* __restrict__ a_src, const float* __restrict__ a_dst,
                                              float* __restrict__ asrc, float* __restrict__ adst){
    int w = threadIdx.x >> 6, lane = threadIdx.x & 63;
    int n = blockIdx.x*4 + w; if (n >= Nn) return;
    const float* hr = &h1[(size_t)n*256];
    #pragma unroll
    for (int h = 0; h < 4; h++){
        float v = hr[h*64 + lane];
        float ps = v * a_src[h*64 + lane];
        float pd = v * a_dst[h*64 + lane];
        #pragma unroll
        for (int m = 32; m > 0; m >>= 1){ ps += __shfl_xor(ps, m); pd += __shfl_xor(pd, m); }
        if (lane == 0){ asrc[n*4+h] = ps; adst[n*4+h] = pd; }
    }
}

__global__ __launch_bounds__(256) void k_att2(const float* __restrict__ h2,
                                              const float* __restrict__ a_src, const float* __restrict__ a_dst,
                                              float* __restrict__ asrc, float* __restrict__ adst){
    int w = threadIdx.x >> 6, lane = threadIdx.x & 63;
    int n = blockIdx.x*4 + w; if (n >= Nn) return;
    float v = h2[(size_t)n*64 + lane];
    float ps = v * a_src[lane];
    float pd = v * a_dst[lane];
    #pragma unroll
    for (int m = 32; m > 0; m >>= 1){ ps += __shfl_xor(ps, m); pd += __shfl_xor(pd, m); }
    if (lane == 0){ asrc[n] = ps; adst[n] = pd; }
}

// ---------------- aggregation: one wave per dst node ----------------
__global__ __launch_bounds__(256) void k_aggr1(const float* __restrict__ h1,
                                               const float* __restrict__ asrc, const float* __restrict__ adst,
                                               const int* __restrict__ rowptr, const int* __restrict__ csr,
                                               const float* __restrict__ b1, float* __restrict__ g1){
    int w = threadIdx.x >> 6, lane = threadIdx.x & 63;
    int i = blockIdx.x*4 + w; if (i >= Nn) return;
    float4 ad = *(const float4*)&adst[i*4];
    float4 as = *(const float4*)&asrc[i*4];
    // self loop
    float p0 = __expf(lrelu(as.x + ad.x));
    float p1 = __expf(lrelu(as.y + ad.y));
    float p2 = __expf(lrelu(as.z + ad.z));
    float p3 = __expf(lrelu(as.w + ad.w));
    const float* hr = &h1[(size_t)i*256];
    float acc0 = p0*hr[lane], acc1 = p1*hr[64+lane], acc2 = p2*hr[128+lane], acc3 = p3*hr[192+lane];
    float s0 = p0, s1 = p1, s2 = p2, s3 = p3;
    int beg = rowptr[i], end = rowptr[i+1];
    for (int j = beg; j < end; j++){
        int s = csr[j];
        float4 a4 = *(const float4*)&asrc[s*4];
        float q0 = __expf(lrelu(a4.x + ad.x));
        float q1 = __expf(lrelu(a4.y + ad.y));
        float q2 = __expf(lrelu(a4.z + ad.z));
        float q3 = __expf(lrelu(a4.w + ad.w));
        const float* hs = &h1[(size_t)s*256];
        acc0 += q0*hs[lane]; acc1 += q1*hs[64+lane]; acc2 += q2*hs[128+lane]; acc3 += q3*hs[192+lane];
        s0 += q0; s1 += q1; s2 += q2; s3 += q3;
    }
    float o0 = acc0/(s0 + 1e-16f) + b1[lane];
    float o1 = acc1/(s1 + 1e-16f) + b1[64+lane];
    float o2 = acc2/(s2 + 1e-16f) + b1[128+lane];
    float o3 = acc3/(s3 + 1e-16f) + b1[192+lane];
    float* gr = &g1[(size_t)i*256];
    gr[lane]     = o0 > 0.f ? o0 : expm1f(o0);
    gr[64+lane]  = o1 > 0.f ? o1 : expm1f(o1);
    gr[128+lane] = o2 > 0.f ? o2 : expm1f(o2);
    gr[192+lane] = o3 > 0.f ? o3 : expm1f(o3);
}

__global__ __launch_bounds__(256) void k_aggr2(const float* __restrict__ h2,
                                               const float* __restrict__ asrc, const float* __restrict__ adst,
                                               const int* __restrict__ rowptr, const int* __restrict__ csr,
                                               const float* __restrict__ b2, float* __restrict__ g2){
    int w = threadIdx.x >> 6, lane = threadIdx.x & 63;
    int i = blockIdx.x*4 + w; if (i >= Nn) return;
    float ad = adst[i];
    float p = __expf(lrelu(asrc[i] + ad));
    float acc = p * h2[(size_t)i*64 + lane];
    float ss = p;
    int beg = rowptr[i], end = rowptr[i+1];
    for (int j = beg; j < end; j++){
        int s = csr[j];
        float q = __expf(lrelu(asrc[s] + ad));
        acc += q * h2[(size_t)s*64 + lane];
        ss += q;
    }
    g2[(size_t)i*64 + lane] = acc/(ss + 1e-16f) + b2[lane];
}

// ---------------- pooling + head ----------------
#define POOL_CH 128
__global__ __launch_bounds__(256) void k_pool(const float* __restrict__ g2, const int* __restrict__ batch,
                                              float* __restrict__ pooled, int* __restrict__ cnt){
    int w = threadIdx.x >> 6, lane = threadIdx.x & 63;
    int chunk = blockIdx.x*4 + w;
    int n0 = chunk*POOL_CH; if (n0 >= Nn) return;
    int n1 = min(n0 + POOL_CH, Nn);
    int cur = batch[n0];
    float acc = 0.f; int count = 0;
    for (int n = n0; n < n1; n++){
        int b = batch[n];
        if (b != cur){
            atomicAdd(&pooled[cur*64 + lane], acc);
            if (lane == 0) atomicAdd(&cnt[cur], count);
            acc = 0.f; count = 0; cur = b;
        }
        acc += g2[(size_t)n*64 + lane];
        count++;
    }
    atomicAdd(&pooled[cur*64 + lane], acc);
    if (lane == 0) atomicAdd(&cnt[cur], count);
}

__global__ void k_final(const float* __restrict__ pooled, const int* __restrict__ cnt,
                        const float* __restrict__ fcW, const float* __restrict__ fcb,
                        float* __restrict__ out){
    int t = threadIdx.x;       // 1024 threads: 64 graphs x 16 classes
    int g = t >> 4, c = t & 15;
    float inv = 1.0f / fmaxf((float)cnt[g], 1.0f);
    float acc = 0.f;
    for (int d = 0; d < 64; d++) acc += pooled[g*64 + d]*inv*fcW[d*16 + c];
    out[g*16 + c] = acc + fcb[c];
}

extern "C" void kernel_launch(void* const* d_in, const int* in_sizes, int n_in,
                              void* d_out, int out_size, void* d_ws, size_t ws_size,
                              hipStream_t stream) {
    const float* x      = (const float*)d_in[0];
    const int*   ei     = (const int*)d_in[1];   // [2][E]: ei = src, ei+Ed = dst
    const int*   batch  = (const int*)d_in[2];
    const float* W1     = (const float*)d_in[3];
    const float* a_src1 = (const float*)d_in[4];
    const float* a_dst1 = (const float*)d_in[5];
    const float* b1     = (const float*)d_in[6];
    const float* W2     = (const float*)d_in[7];
    const float* a_src2 = (const float*)d_in[8];
    const float* a_dst2 = (const float*)d_in[9];
    const float* b2     = (const float*)d_in[10];
    const float* fcW    = (const float*)d_in[11];
    const float* fcb    = (const float*)d_in[12];
    float* out = (float*)d_out;

    char* ws = (char*)d_ws;
    size_t off = 0;
    auto carve = [&](size_t bytes)->void*{
        void* p = ws + off;
        off += (bytes + 255) & ~(size_t)255;
        return p;
    };
    float* h1     = (float*)carve((size_t)Nn*256*4);   // x@W1
    float* g1     = (float*)carve((size_t)Nn*256*4);   // elu(gat1 out)
    float* h2     = (float*)carve((size_t)Nn*64*4);    // g1@W2
    float* g2     = (float*)carve((size_t)Nn*64*4);    // gat2 out
    float* asrc1  = (float*)carve((size_t)Nn*4*4);
    float* adst1  = (float*)carve((size_t)Nn*4*4);
    float* asrc2  = (float*)carve((size_t)Nn*4);
    float* adst2  = (float*)carve((size_t)Nn*4);
    int*   deg    = (int*)carve((size_t)Nn*4);
    int*   rowptr = (int*)carve((size_t)(Nn+1)*4);
    int*   cursor = (int*)carve((size_t)Nn*4);
    int*   csr    = (int*)carve((size_t)Ed*4);
    float* pooled = (float*)carve(64*64*4);
    int*   cnt    = (int*)carve(64*4);

    hipMemsetAsync(deg, 0, (size_t)Nn*4, stream);
    hipMemsetAsync(pooled, 0, 64*64*4, stream);
    hipMemsetAsync(cnt, 0, 64*4, stream);

    const int EB = (Ed + 255)/256;
    const int NB4 = (Nn + 3)/4;

    k_degree<<<EB, 256, 0, stream>>>(ei + Ed, deg);
    k_scan<<<1, 1024, 0, stream>>>(deg, rowptr, cursor);
    k_scatter<<<EB, 256, 0, stream>>>(ei, ei + Ed, cursor, csr);

    k_gemm<128,256><<<dim3((Nn+63)/64, 4), 256, 0, stream>>>(x, W1, h1);
    k_att1<<<NB4, 256, 0, stream>>>(h1, a_src1, a_dst1, asrc1, adst1);
    k_aggr1<<<NB4, 256, 0, stream>>>(h1, asrc1, adst1, rowptr, csr, b1, g1);

    k_gemm<256,64><<<dim3((Nn+63)/64, 1), 256, 0, stream>>>(g1, W2, h2);
    k_att2<<<NB4, 256, 0, stream>>>(h2, a_src2, a_dst2, asrc2, adst2);
    k_aggr2<<<NB4, 256, 0, stream>>>(h2, asrc2, adst2, rowptr, csr, b2, g2);

    const int NCH = (Nn + POOL_CH - 1)/POOL_CH;   // 391
    k_pool<<<(NCH+3)/4, 256, 0, stream>>>(g2, batch, pooled, cnt);
    k_final<<<1, 1024, 0, stream>>>(pooled, cnt, fcW, fcb, out);
}

// Round 2
// 602.361 us; speedup vs baseline: 1.1255x; 1.1255x over previous
//
#include <hip/hip_runtime.h>
#include <hip/hip_bf16.h>

// GAT classifier: 2x GATConv + global_mean_pool + linear.
// N=50000 nodes, E=800000 edges, IN=128, HID=64, HEADS=4, CLASSES=16, GRAPHS=64.
// R2: gathered features (h1,h2) stored bf16 -> halves the edge-gather traffic
// (the measured bottleneck: aggr1 FETCH 430MB @3.6TB/s). Accumulation fp32.

#define Nn 50000
#define Ed 800000
#define NEG 0.2f

__device__ __forceinline__ float lrelu(float x){ return fmaxf(x, NEG*x); }
__device__ __forceinline__ float bf2f(unsigned short u){ return __uint_as_float((unsigned)u << 16); }
__device__ __forceinline__ unsigned short f2bf(float f){
    __hip_bfloat16 b = __float2bfloat16(f);
    return *reinterpret_cast<unsigned short*>(&b);
}

// ---------------- CSR build ----------------
__global__ void k_degree(const int* __restrict__ dst, int* __restrict__ deg){
    int e = blockIdx.x*256 + threadIdx.x;
    if (e < Ed) atomicAdd(&deg[dst[e]], 1);
}

__global__ void k_scan(const int* __restrict__ deg, int* __restrict__ rowptr, int* __restrict__ cursor){
    __shared__ int sums[1024];
    int tid = threadIdx.x;
    const int CH = (Nn + 1023)/1024; // 49
    int start = tid*CH;
    int s = 0;
    for (int i = 0; i < CH; i++){ int idx = start+i; if (idx < Nn) s += deg[idx]; }
    sums[tid] = s; __syncthreads();
    for (int off = 1; off < 1024; off <<= 1){
        int v = (tid >= off) ? sums[tid-off] : 0;
        __syncthreads();
        sums[tid] += v;
        __syncthreads();
    }
    int run = sums[tid] - s; // exclusive
    for (int i = 0; i < CH; i++){
        int idx = start+i;
        if (idx < Nn){ rowptr[idx] = run; cursor[idx] = run; run += deg[idx]; }
    }
    if (tid == 1023) rowptr[Nn] = sums[1023];
}

__global__ void k_scatter(const int* __restrict__ src, const int* __restrict__ dst,
                          int* __restrict__ cursor, int* __restrict__ csr){
    int e = blockIdx.x*256 + threadIdx.x;
    if (e < Ed){
        int pos = atomicAdd(&cursor[dst[e]], 1);
        csr[pos] = src[e];
    }
}

// ---------------- fp32 GEMM: C[Nn,NC] = A[Nn,K] @ B[K,NC], tile 64x64, K-chunk 64 --------
// OUTBF: store C as bf16 (RNE) instead of fp32.
template<int K, int NC, bool OUTBF>
__global__ __launch_bounds__(256) void k_gemm(const float* __restrict__ A, const float* __restrict__ B,
                                              void* __restrict__ Cv){
    __shared__ float As[64][68];
    __shared__ float Bs[64][64];
    const int tid = threadIdx.x;
    const int row0 = blockIdx.x*64;
    const int col0 = blockIdx.y*64;
    const int tx = tid & 15, ty = tid >> 4;
    float acc[4][4] = {};
    for (int kc = 0; kc < K; kc += 64){
        for (int g = tid; g < 1024; g += 256){
            int r = g >> 4, c4 = (g & 15) << 2;
            int row = row0 + r;
            float4 av = make_float4(0.f,0.f,0.f,0.f);
            if (row < Nn) av = *(const float4*)&A[(size_t)row*K + kc + c4];
            *(float4*)&As[r][c4] = av;
            *(float4*)&Bs[r][c4] = *(const float4*)&B[(size_t)(kc + r)*NC + col0 + c4];
        }
        __syncthreads();
        #pragma unroll
        for (int k = 0; k < 64; k += 4){
            float a_[4][4];
            #pragma unroll
            for (int i = 0; i < 4; i++){
                float4 t = *(const float4*)&As[ty*4+i][k];
                a_[i][0]=t.x; a_[i][1]=t.y; a_[i][2]=t.z; a_[i][3]=t.w;
            }
            #pragma unroll
            for (int kk = 0; kk < 4; kk++){
                float4 b = *(const float4*)&Bs[k+kk][tx*4];
                float bb[4] = {b.x, b.y, b.z, b.w};
                #pragma unroll
                for (int i = 0; i < 4; i++)
                    #pragma unroll
                    for (int j = 0; j < 4; j++)
                        acc[i][j] += a_[i][kk]*bb[j];
            }
        }
        __syncthreads();
    }
    #pragma unroll
    for (int i = 0; i < 4; i++){
        int row = row0 + ty*4 + i;
        if (row < Nn){
            if constexpr (OUTBF){
                unsigned short* C = (unsigned short*)Cv;
                ushort4 o;
                o.x = f2bf(acc[i][0]); o.y = f2bf(acc[i][1]);
                o.z = f2bf(acc[i][2]); o.w = f2bf(acc[i][3]);
                *(ushort4*)&C[(size_t)row*NC + col0 + tx*4] = o;
            } else {
                float* C = (float*)Cv;
                float4 o = make_float4(acc[i][0], acc[i][1], acc[i][2], acc[i][3]);
                *(float4*)&C[(size_t)row*NC + col0 + tx*4] = o;
            }
        }
    }
}

// ---------------- attention coefficients (bf16 h input) ----------------
__global__ __launch_bounds__(256) void k_att1(const unsigned short* __restrict__ h1,
                                              const float* __restrict__ a_src, const float* __restrict__ a_dst,
                                              float* __restrict__ asrc, float* __restrict__ adst){
    int w = threadIdx.x >> 6, lane = threadIdx.x & 63;
    int n = blockIdx.x*4 + w; if (n >= Nn) return;
    const unsigned short* hr = &h1[(size_t)n*256];
    #pragma unroll
    for (int h = 0; h < 4; h++){
        float v = bf2f(hr[h*64 + lane]);
        float ps = v * a_src[h*64 + lane];
        float pd = v * a_dst[h*64 + lane];
        #pragma unroll
        for (int m = 32; m > 0; m >>= 1){ ps += __shfl_xor(ps, m); pd += __shfl_xor(pd, m); }
        if (lane == 0){ asrc[n*4+h] = ps; adst[n*4+h] = pd; }
    }
}

__global__ __launch_bounds__(256) void k_att2(const unsigned short* __restrict__ h2,
                                              const float* __restrict__ a_src, const float* __restrict__ a_dst,
                                              float* __restrict__ asrc, float* __restrict__ adst){
    int w = threadIdx.x >> 6, lane = threadIdx.x & 63;
    int n = blockIdx.x*4 + w; if (n >= Nn) return;
    float v = bf2f(h2[(size_t)n*64 + lane]);
    float ps = v * a_src[lane];
    float pd = v * a_dst[lane];
    #pragma unroll
    for (int m = 32; m > 0; m >>= 1){ ps += __shfl_xor(ps, m); pd += __shfl_xor(pd, m); }
    if (lane == 0){ asrc[n] = ps; adst[n] = pd; }
}

// ---------------- aggregation layer 1: one wave per dst node ----------------
// Lane l owns dims [4l,4l+4) of the flattened 256 -> head = l>>4.
// One expf per edge per lane; 8B ushort4 gather per lane (512B/row/wave).
__global__ __launch_bounds__(256) void k_aggr1(const unsigned short* __restrict__ h1,
                                               const float* __restrict__ asrc, const float* __restrict__ adst,
                                               const int* __restrict__ rowptr, const int* __restrict__ csr,
                                               const float* __restrict__ b1, float* __restrict__ g1){
    int w = threadIdx.x >> 6, lane = threadIdx.x & 63;
    int i = blockIdx.x*4 + w; if (i >= Nn) return;
    int hh = lane >> 4;
    float ad = adst[i*4 + hh];
    float as = asrc[i*4 + hh];
    float p = __expf(lrelu(as + ad));
    ushort4 hv = *(const ushort4*)&h1[(size_t)i*256 + 4*lane];
    float acc0 = p*bf2f(hv.x), acc1 = p*bf2f(hv.y), acc2 = p*bf2f(hv.z), acc3 = p*bf2f(hv.w);
    float ssum = p;
    int beg = rowptr[i], end = rowptr[i+1];
    int j = beg;
    for (; j + 1 < end; j += 2){
        int s0 = csr[j], s1 = csr[j+1];
        float a0 = asrc[s0*4 + hh];
        float a1 = asrc[s1*4 + hh];
        ushort4 v0 = *(const ushort4*)&h1[(size_t)s0*256 + 4*lane];
        ushort4 v1 = *(const ushort4*)&h1[(size_t)s1*256 + 4*lane];
        float q0 = __expf(lrelu(a0 + ad));
        float q1 = __expf(lrelu(a1 + ad));
        acc0 += q0*bf2f(v0.x) + q1*bf2f(v1.x);
        acc1 += q0*bf2f(v0.y) + q1*bf2f(v1.y);
        acc2 += q0*bf2f(v0.z) + q1*bf2f(v1.z);
        acc3 += q0*bf2f(v0.w) + q1*bf2f(v1.w);
        ssum += q0 + q1;
    }
    if (j < end){
        int s = csr[j];
        float a = asrc[s*4 + hh];
        ushort4 v = *(const ushort4*)&h1[(size_t)s*256 + 4*lane];
        float q = __expf(lrelu(a + ad));
        acc0 += q*bf2f(v.x); acc1 += q*bf2f(v.y);
        acc2 += q*bf2f(v.z); acc3 += q*bf2f(v.w);
        ssum += q;
    }
    float inv = 1.0f/(ssum + 1e-16f);
    float4 b4 = *(const float4*)&b1[4*lane];
    float o0 = acc0*inv + b4.x;
    float o1 = acc1*inv + b4.y;
    float o2 = acc2*inv + b4.z;
    float o3 = acc3*inv + b4.w;
    float4 o;
    o.x = o0 > 0.f ? o0 : expm1f(o0);
    o.y = o1 > 0.f ? o1 : expm1f(o1);
    o.z = o2 > 0.f ? o2 : expm1f(o2);
    o.w = o3 > 0.f ? o3 : expm1f(o3);
    *(float4*)&g1[(size_t)i*256 + 4*lane] = o;
}

// ---------------- aggregation layer 2: one wave per dst node, dim = lane ----------------
__global__ __launch_bounds__(256) void k_aggr2(const unsigned short* __restrict__ h2,
                                               const float* __restrict__ asrc, const float* __restrict__ adst,
                                               const int* __restrict__ rowptr, const int* __restrict__ csr,
                                               const float* __restrict__ b2, float* __restrict__ g2){
    int w = threadIdx.x >> 6, lane = threadIdx.x & 63;
    int i = blockIdx.x*4 + w; if (i >= Nn) return;
    float ad = adst[i];
    float p = __expf(lrelu(asrc[i] + ad));
    float acc = p * bf2f(h2[(size_t)i*64 + lane]);
    float ss = p;
    int beg = rowptr[i], end = rowptr[i+1];
    int j = beg;
    for (; j + 1 < end; j += 2){
        int s0 = csr[j], s1 = csr[j+1];
        float a0 = asrc[s0], a1 = asrc[s1];
        unsigned short v0 = h2[(size_t)s0*64 + lane];
        unsigned short v1 = h2[(size_t)s1*64 + lane];
        float q0 = __expf(lrelu(a0 + ad));
        float q1 = __expf(lrelu(a1 + ad));
        acc += q0*bf2f(v0) + q1*bf2f(v1);
        ss += q0 + q1;
    }
    if (j < end){
        int s = csr[j];
        float q = __expf(lrelu(asrc[s] + ad));
        acc += q * bf2f(h2[(size_t)s*64 + lane]);
        ss += q;
    }
    g2[(size_t)i*64 + lane] = acc/(ss + 1e-16f) + b2[lane];
}

// ---------------- pooling + head ----------------
#define POOL_CH 128
__global__ __launch_bounds__(256) void k_pool(const float* __restrict__ g2, const int* __restrict__ batch,
                                              float* __restrict__ pooled, int* __restrict__ cnt){
    int w = threadIdx.x >> 6, lane = threadIdx.x & 63;
    int chunk = blockIdx.x*4 + w;
    int n0 = chunk*POOL_CH; if (n0 >= Nn) return;
    int n1 = min(n0 + POOL_CH, Nn);
    int cur = batch[n0];
    float acc = 0.f; int count = 0;
    for (int n = n0; n < n1; n++){
        int b = batch[n];
        if (b != cur){
            atomicAdd(&pooled[cur*64 + lane], acc);
            if (lane == 0) atomicAdd(&cnt[cur], count);
            acc = 0.f; count = 0; cur = b;
        }
        acc += g2[(size_t)n*64 + lane];
        count++;
    }
    atomicAdd(&pooled[cur*64 + lane], acc);
    if (lane == 0) atomicAdd(&cnt[cur], count);
}

__global__ void k_final(const float* __restrict__ pooled, const int* __restrict__ cnt,
                        const float* __restrict__ fcW, const float* __restrict__ fcb,
                        float* __restrict__ out){
    int t = threadIdx.x;       // 1024 threads: 64 graphs x 16 classes
    int g = t >> 4, c = t & 15;
    float inv = 1.0f / fmaxf((float)cnt[g], 1.0f);
    float acc = 0.f;
    for (int d = 0; d < 64; d++) acc += pooled[g*64 + d]*inv*fcW[d*16 + c];
    out[g*16 + c] = acc + fcb[c];
}

extern "C" void kernel_launch(void* const* d_in, const int* in_sizes, int n_in,
                              void* d_out, int out_size, void* d_ws, size_t ws_size,
                              hipStream_t stream) {
    const float* x      = (const float*)d_in[0];
    const int*   ei     = (const int*)d_in[1];   // [2][E]: ei = src, ei+Ed = dst
    const int*   batch  = (const int*)d_in[2];
    const float* W1     = (const float*)d_in[3];
    const float* a_src1 = (const float*)d_in[4];
    const float* a_dst1 = (const float*)d_in[5];
    const float* b1     = (const float*)d_in[6];
    const float* W2     = (const float*)d_in[7];
    const float* a_src2 = (const float*)d_in[8];
    const float* a_dst2 = (const float*)d_in[9];
    const float* b2     = (const float*)d_in[10];
    const float* fcW    = (const float*)d_in[11];
    const float* fcb    = (const float*)d_in[12];
    float* out = (float*)d_out;

    char* ws = (char*)d_ws;
    size_t off = 0;
    auto carve = [&](size_t bytes)->void*{
        void* p = ws + off;
        off += (bytes + 255) & ~(size_t)255;
        return p;
    };
    unsigned short* h1b = (unsigned short*)carve((size_t)Nn*256*2); // x@W1, bf16
    float*          g1  = (float*)carve((size_t)Nn*256*4);          // elu(gat1 out), fp32
    unsigned short* h2b = (unsigned short*)carve((size_t)Nn*64*2);  // g1@W2, bf16
    float*          g2  = (float*)carve((size_t)Nn*64*4);           // gat2 out, fp32
    float* asrc1  = (float*)carve((size_t)Nn*4*4);
    float* adst1  = (float*)carve((size_t)Nn*4*4);
    float* asrc2  = (float*)carve((size_t)Nn*4);
    float* adst2  = (float*)carve((size_t)Nn*4);
    int*   deg    = (int*)carve((size_t)Nn*4);
    int*   rowptr = (int*)carve((size_t)(Nn+1)*4);
    int*   cursor = (int*)carve((size_t)Nn*4);
    int*   csr    = (int*)carve((size_t)Ed*4);
    float* pooled = (float*)carve(64*64*4);
    int*   cnt    = (int*)carve(64*4);

    hipMemsetAsync(deg, 0, (size_t)Nn*4, stream);
    hipMemsetAsync(pooled, 0, 64*64*4, stream);
    hipMemsetAsync(cnt, 0, 64*4, stream);

    const int EB = (Ed + 255)/256;
    const int NB4 = (Nn + 3)/4;

    k_degree<<<EB, 256, 0, stream>>>(ei + Ed, deg);
    k_scan<<<1, 1024, 0, stream>>>(deg, rowptr, cursor);
    k_scatter<<<EB, 256, 0, stream>>>(ei, ei + Ed, cursor, csr);

    k_gemm<128,256,true><<<dim3((Nn+63)/64, 4), 256, 0, stream>>>(x, W1, h1b);
    k_att1<<<NB4, 256, 0, stream>>>(h1b, a_src1, a_dst1, asrc1, adst1);
    k_aggr1<<<NB4, 256, 0, stream>>>(h1b, asrc1, adst1, rowptr, csr, b1, g1);

    k_gemm<256,64,true><<<dim3((Nn+63)/64, 1), 256, 0, stream>>>(g1, W2, h2b);
    k_att2<<<NB4, 256, 0, stream>>>(h2b, a_src2, a_dst2, asrc2, adst2);
    k_aggr2<<<NB4, 256, 0, stream>>>(h2b, asrc2, adst2, rowptr, csr, b2, g2);

    const int NCH = (Nn + POOL_CH - 1)/POOL_CH;   // 391
    k_pool<<<(NCH+3)/4, 256, 0, stream>>>(g2, batch, pooled, cnt);
    k_final<<<1, 1024, 0, stream>>>(pooled, cnt, fcW, fcb, out);
}

// Round 3
// 494.494 us; speedup vs baseline: 1.3710x; 1.2181x over previous
//
#include <hip/hip_runtime.h>
#include <hip/hip_bf16.h>

// GAT classifier: 2x GATConv + global_mean_pool + linear.
// N=50000 nodes, E=800000 edges, IN=128, HID=64, HEADS=4, CLASSES=16, GRAPHS=64.
// R2: bf16 gathered features (halved aggr gather traffic). R3: replace the
// single-block 128us prefix scan with a 3-kernel device-wide scan (~8us).

#define Nn 50000
#define Ed 800000
#define NEG 0.2f
#define SCAN_B 196   // ceil(50000/256)

__device__ __forceinline__ float lrelu(float x){ return fmaxf(x, NEG*x); }
__device__ __forceinline__ float bf2f(unsigned short u){ return __uint_as_float((unsigned)u << 16); }
__device__ __forceinline__ unsigned short f2bf(float f){
    __hip_bfloat16 b = __float2bfloat16(f);
    return *reinterpret_cast<unsigned short*>(&b);
}

// ---------------- CSR build ----------------
__global__ void k_degree(const int* __restrict__ dst, int* __restrict__ deg){
    int e = blockIdx.x*256 + threadIdx.x;
    if (e < Ed) atomicAdd(&deg[dst[e]], 1);
}

// 1) per-block sums of deg (256 elements per block)
__global__ __launch_bounds__(256) void k_partial(const int* __restrict__ deg, int* __restrict__ partial){
    __shared__ int red[256];
    int tid = threadIdx.x;
    int g = blockIdx.x*256 + tid;
    red[tid] = (g < Nn) ? deg[g] : 0;
    __syncthreads();
    for (int off = 128; off > 0; off >>= 1){
        if (tid < off) red[tid] += red[tid+off];
        __syncthreads();
    }
    if (tid == 0) partial[blockIdx.x] = red[0];
}

// 2) exclusive scan of the SCAN_B partials; also write rowptr[Nn]=total
__global__ __launch_bounds__(256) void k_scanpartials(const int* __restrict__ partial,
                                                      int* __restrict__ psum, int* __restrict__ rowptr){
    __shared__ int s[256];
    int tid = threadIdx.x;
    int v = (tid < SCAN_B) ? partial[tid] : 0;
    s[tid] = v; __syncthreads();
    for (int off = 1; off < 256; off <<= 1){
        int t = (tid >= off) ? s[tid-off] : 0;
        __syncthreads();
        s[tid] += t;
        __syncthreads();
    }
    if (tid < SCAN_B) psum[tid] = s[tid] - v;   // exclusive
    if (tid == 255) rowptr[Nn] = s[255];
}

// 3) per-block LDS scan + block offset -> rowptr/cursor, coalesced
__global__ __launch_bounds__(256) void k_apply(const int* __restrict__ deg, const int* __restrict__ psum,
                                               int* __restrict__ rowptr, int* __restrict__ cursor){
    __shared__ int s[256];
    int tid = threadIdx.x;
    int g = blockIdx.x*256 + tid;
    int v = (g < Nn) ? deg[g] : 0;
    s[tid] = v; __syncthreads();
    for (int off = 1; off < 256; off <<= 1){
        int t = (tid >= off) ? s[tid-off] : 0;
        __syncthreads();
        s[tid] += t;
        __syncthreads();
    }
    if (g < Nn){
        int ex = s[tid] - v + psum[blockIdx.x];
        rowptr[g] = ex;
        cursor[g] = ex;
    }
}

__global__ void k_scatter(const int* __restrict__ src, const int* __restrict__ dst,
                          int* __restrict__ cursor, int* __restrict__ csr){
    int e = blockIdx.x*256 + threadIdx.x;
    if (e < Ed){
        int pos = atomicAdd(&cursor[dst[e]], 1);
        csr[pos] = src[e];
    }
}

// ---------------- fp32 GEMM: C[Nn,NC] = A[Nn,K] @ B[K,NC], tile 64x64, K-chunk 64 --------
// OUTBF: store C as bf16 (RNE) instead of fp32.
template<int K, int NC, bool OUTBF>
__global__ __launch_bounds__(256) void k_gemm(const float* __restrict__ A, const float* __restrict__ B,
                                              void* __restrict__ Cv){
    __shared__ float As[64][68];
    __shared__ float Bs[64][64];
    const int tid = threadIdx.x;
    const int row0 = blockIdx.x*64;
    const int col0 = blockIdx.y*64;
    const int tx = tid & 15, ty = tid >> 4;
    float acc[4][4] = {};
    for (int kc = 0; kc < K; kc += 64){
        for (int g = tid; g < 1024; g += 256){
            int r = g >> 4, c4 = (g & 15) << 2;
            int row = row0 + r;
            float4 av = make_float4(0.f,0.f,0.f,0.f);
            if (row < Nn) av = *(const float4*)&A[(size_t)row*K + kc + c4];
            *(float4*)&As[r][c4] = av;
            *(float4*)&Bs[r][c4] = *(const float4*)&B[(size_t)(kc + r)*NC + col0 + c4];
        }
        __syncthreads();
        #pragma unroll
        for (int k = 0; k < 64; k += 4){
            float a_[4][4];
            #pragma unroll
            for (int i = 0; i < 4; i++){
                float4 t = *(const float4*)&As[ty*4+i][k];
                a_[i][0]=t.x; a_[i][1]=t.y; a_[i][2]=t.z; a_[i][3]=t.w;
            }
            #pragma unroll
            for (int kk = 0; kk < 4; kk++){
                float4 b = *(const float4*)&Bs[k+kk][tx*4];
                float bb[4] = {b.x, b.y, b.z, b.w};
                #pragma unroll
                for (int i = 0; i < 4; i++)
                    #pragma unroll
                    for (int j = 0; j < 4; j++)
                        acc[i][j] += a_[i][kk]*bb[j];
            }
        }
        __syncthreads();
    }
    #pragma unroll
    for (int i = 0; i < 4; i++){
        int row = row0 + ty*4 + i;
        if (row < Nn){
            if constexpr (OUTBF){
                unsigned short* C = (unsigned short*)Cv;
                ushort4 o;
                o.x = f2bf(acc[i][0]); o.y = f2bf(acc[i][1]);
                o.z = f2bf(acc[i][2]); o.w = f2bf(acc[i][3]);
                *(ushort4*)&C[(size_t)row*NC + col0 + tx*4] = o;
            } else {
                float* C = (float*)Cv;
                float4 o = make_float4(acc[i][0], acc[i][1], acc[i][2], acc[i][3]);
                *(float4*)&C[(size_t)row*NC + col0 + tx*4] = o;
            }
        }
    }
}

// ---------------- attention coefficients (bf16 h input) ----------------
__global__ __launch_bounds__(256) void k_att1(const unsigned short* __restrict__ h1,
                                              const float* __restrict__ a_src, const float* __restrict__ a_dst,
                                              float* __restrict__ asrc, float* __restrict__ adst){
    int w = threadIdx.x >> 6, lane = threadIdx.x & 63;
    int n = blockIdx.x*4 + w; if (n >= Nn) return;
    const unsigned short* hr = &h1[(size_t)n*256];
    #pragma unroll
    for (int h = 0; h < 4; h++){
        float v = bf2f(hr[h*64 + lane]);
        float ps = v * a_src[h*64 + lane];
        float pd = v * a_dst[h*64 + lane];
        #pragma unroll
        for (int m = 32; m > 0; m >>= 1){ ps += __shfl_xor(ps, m); pd += __shfl_xor(pd, m); }
        if (lane == 0){ asrc[n*4+h] = ps; adst[n*4+h] = pd; }
    }
}

__global__ __launch_bounds__(256) void k_att2(const unsigned short* __restrict__ h2,
                                              const float* __restrict__ a_src, const float* __restrict__ a_dst,
                                              float* __restrict__ asrc, float* __restrict__ adst){
    int w = threadIdx.x >> 6, lane = threadIdx.x & 63;
    int n = blockIdx.x*4 + w; if (n >= Nn) return;
    float v = bf2f(h2[(size_t)n*64 + lane]);
    float ps = v * a_src[lane];
    float pd = v * a_dst[lane];
    #pragma unroll
    for (int m = 32; m > 0; m >>= 1){ ps += __shfl_xor(ps, m); pd += __shfl_xor(pd, m); }
    if (lane == 0){ asrc[n] = ps; adst[n] = pd; }
}

// ---------------- aggregation layer 1: one wave per dst node ----------------
// Lane l owns dims [4l,4l+4) of the flattened 256 -> head = l>>4.
__global__ __launch_bounds__(256) void k_aggr1(const unsigned short* __restrict__ h1,
                                               const float* __restrict__ asrc, const float* __restrict__ adst,
                                               const int* __restrict__ rowptr, const int* __restrict__ csr,
                                               const float* __restrict__ b1, float* __restrict__ g1){
    int w = threadIdx.x >> 6, lane = threadIdx.x & 63;
    int i = blockIdx.x*4 + w; if (i >= Nn) return;
    int hh = lane >> 4;
    float ad = adst[i*4 + hh];
    float as = asrc[i*4 + hh];
    float p = __expf(lrelu(as + ad));
    ushort4 hv = *(const ushort4*)&h1[(size_t)i*256 + 4*lane];
    float acc0 = p*bf2f(hv.x), acc1 = p*bf2f(hv.y), acc2 = p*bf2f(hv.z), acc3 = p*bf2f(hv.w);
    float ssum = p;
    int beg = rowptr[i], end = rowptr[i+1];
    int j = beg;
    for (; j + 1 < end; j += 2){
        int s0 = csr[j], s1 = csr[j+1];
        float a0 = asrc[s0*4 + hh];
        float a1 = asrc[s1*4 + hh];
        ushort4 v0 = *(const ushort4*)&h1[(size_t)s0*256 + 4*lane];
        ushort4 v1 = *(const ushort4*)&h1[(size_t)s1*256 + 4*lane];
        float q0 = __expf(lrelu(a0 + ad));
        float q1 = __expf(lrelu(a1 + ad));
        acc0 += q0*bf2f(v0.x) + q1*bf2f(v1.x);
        acc1 += q0*bf2f(v0.y) + q1*bf2f(v1.y);
        acc2 += q0*bf2f(v0.z) + q1*bf2f(v1.z);
        acc3 += q0*bf2f(v0.w) + q1*bf2f(v1.w);
        ssum += q0 + q1;
    }
    if (j < end){
        int s = csr[j];
        float a = asrc[s*4 + hh];
        ushort4 v = *(const ushort4*)&h1[(size_t)s*256 + 4*lane];
        float q = __expf(lrelu(a + ad));
        acc0 += q*bf2f(v.x); acc1 += q*bf2f(v.y);
        acc2 += q*bf2f(v.z); acc3 += q*bf2f(v.w);
        ssum += q;
    }
    float inv = 1.0f/(ssum + 1e-16f);
    float4 b4 = *(const float4*)&b1[4*lane];
    float o0 = acc0*inv + b4.x;
    float o1 = acc1*inv + b4.y;
    float o2 = acc2*inv + b4.z;
    float o3 = acc3*inv + b4.w;
    float4 o;
    o.x = o0 > 0.f ? o0 : expm1f(o0);
    o.y = o1 > 0.f ? o1 : expm1f(o1);
    o.z = o2 > 0.f ? o2 : expm1f(o2);
    o.w = o3 > 0.f ? o3 : expm1f(o3);
    *(float4*)&g1[(size_t)i*256 + 4*lane] = o;
}

// ---------------- aggregation layer 2: one wave per dst node, dim = lane ----------------
__global__ __launch_bounds__(256) void k_aggr2(const unsigned short* __restrict__ h2,
                                               const float* __restrict__ asrc, const float* __restrict__ adst,
                                               const int* __restrict__ rowptr, const int* __restrict__ csr,
                                               const float* __restrict__ b2, float* __restrict__ g2){
    int w = threadIdx.x >> 6, lane = threadIdx.x & 63;
    int i = blockIdx.x*4 + w; if (i >= Nn) return;
    float ad = adst[i];
    float p = __expf(lrelu(asrc[i] + ad));
    float acc = p * bf2f(h2[(size_t)i*64 + lane]);
    float ss = p;
    int beg = rowptr[i], end = rowptr[i+1];
    int j = beg;
    for (; j + 1 < end; j += 2){
        int s0 = csr[j], s1 = csr[j+1];
        float a0 = asrc[s0], a1 = asrc[s1];
        unsigned short v0 = h2[(size_t)s0*64 + lane];
        unsigned short v1 = h2[(size_t)s1*64 + lane];
        float q0 = __expf(lrelu(a0 + ad));
        float q1 = __expf(lrelu(a1 + ad));
        acc += q0*bf2f(v0) + q1*bf2f(v1);
        ss += q0 + q1;
    }
    if (j < end){
        int s = csr[j];
        float q = __expf(lrelu(asrc[s] + ad));
        acc += q * bf2f(h2[(size_t)s*64 + lane]);
        ss += q;
    }
    g2[(size_t)i*64 + lane] = acc/(ss + 1e-16f) + b2[lane];
}

// ---------------- pooling + head ----------------
#define POOL_CH 128
__global__ __launch_bounds__(256) void k_pool(const float* __restrict__ g2, const int* __restrict__ batch,
                                              float* __restrict__ pooled, int* __restrict__ cnt){
    int w = threadIdx.x >> 6, lane = threadIdx.x & 63;
    int chunk = blockIdx.x*4 + w;
    int n0 = chunk*POOL_CH; if (n0 >= Nn) return;
    int n1 = min(n0 + POOL_CH, Nn);
    int cur = batch[n0];
    float acc = 0.f; int count = 0;
    for (int n = n0; n < n1; n++){
        int b = batch[n];
        if (b != cur){
            atomicAdd(&pooled[cur*64 + lane], acc);
            if (lane == 0) atomicAdd(&cnt[cur], count);
            acc = 0.f; count = 0; cur = b;
        }
        acc += g2[(size_t)n*64 + lane];
        count++;
    }
    atomicAdd(&pooled[cur*64 + lane], acc);
    if (lane == 0) atomicAdd(&cnt[cur], count);
}

__global__ void k_final(const float* __restrict__ pooled, const int* __restrict__ cnt,
                        const float* __restrict__ fcW, const float* __restrict__ fcb,
                        float* __restrict__ out){
    int t = threadIdx.x;       // 1024 threads: 64 graphs x 16 classes
    int g = t >> 4, c = t & 15;
    float inv = 1.0f / fmaxf((float)cnt[g], 1.0f);
    float acc = 0.f;
    for (int d = 0; d < 64; d++) acc += pooled[g*64 + d]*inv*fcW[d*16 + c];
    out[g*16 + c] = acc + fcb[c];
}

extern "C" void kernel_launch(void* const* d_in, const int* in_sizes, int n_in,
                              void* d_out, int out_size, void* d_ws, size_t ws_size,
                              hipStream_t stream) {
    const float* x      = (const float*)d_in[0];
    const int*   ei     = (const int*)d_in[1];   // [2][E]: ei = src, ei+Ed = dst
    const int*   batch  = (const int*)d_in[2];
    const float* W1     = (const float*)d_in[3];
    const float* a_src1 = (const float*)d_in[4];
    const float* a_dst1 = (const float*)d_in[5];
    const float* b1     = (const float*)d_in[6];
    const float* W2     = (const float*)d_in[7];
    const float* a_src2 = (const float*)d_in[8];
    const float* a_dst2 = (const float*)d_in[9];
    const float* b2     = (const float*)d_in[10];
    const float* fcW    = (const float*)d_in[11];
    const float* fcb    = (const float*)d_in[12];
    float* out = (float*)d_out;

    char* ws = (char*)d_ws;
    size_t off = 0;
    auto carve = [&](size_t bytes)->void*{
        void* p = ws + off;
        off += (bytes + 255) & ~(size_t)255;
        return p;
    };
    unsigned short* h1b = (unsigned short*)carve((size_t)Nn*256*2); // x@W1, bf16
    float*          g1  = (float*)carve((size_t)Nn*256*4);          // elu(gat1 out), fp32
    unsigned short* h2b = (unsigned short*)carve((size_t)Nn*64*2);  // g1@W2, bf16
    float*          g2  = (float*)carve((size_t)Nn*64*4);           // gat2 out, fp32
    float* asrc1  = (float*)carve((size_t)Nn*4*4);
    float* adst1  = (float*)carve((size_t)Nn*4*4);
    float* asrc2  = (float*)carve((size_t)Nn*4);
    float* adst2  = (float*)carve((size_t)Nn*4);
    int*   deg    = (int*)carve((size_t)Nn*4);
    int*   rowptr = (int*)carve((size_t)(Nn+1)*4);
    int*   cursor = (int*)carve((size_t)Nn*4);
    int*   csr    = (int*)carve((size_t)Ed*4);
    int*   partial= (int*)carve((size_t)SCAN_B*4);
    int*   psum   = (int*)carve((size_t)SCAN_B*4);
    float* pooled = (float*)carve(64*64*4);
    int*   cnt    = (int*)carve(64*4);

    hipMemsetAsync(deg, 0, (size_t)Nn*4, stream);
    hipMemsetAsync(pooled, 0, 64*64*4, stream);
    hipMemsetAsync(cnt, 0, 64*4, stream);

    const int EB = (Ed + 255)/256;
    const int NB4 = (Nn + 3)/4;

    k_degree<<<EB, 256, 0, stream>>>(ei + Ed, deg);
    k_partial<<<SCAN_B, 256, 0, stream>>>(deg, partial);
    k_scanpartials<<<1, 256, 0, stream>>>(partial, psum, rowptr);
    k_apply<<<SCAN_B, 256, 0, stream>>>(deg, psum, rowptr, cursor);
    k_scatter<<<EB, 256, 0, stream>>>(ei, ei + Ed, cursor, csr);

    k_gemm<128,256,true><<<dim3((Nn+63)/64, 4), 256, 0, stream>>>(x, W1, h1b);
    k_att1<<<NB4, 256, 0, stream>>>(h1b, a_src1, a_dst1, asrc1, adst1);
    k_aggr1<<<NB4, 256, 0, stream>>>(h1b, asrc1, adst1, rowptr, csr, b1, g1);

    k_gemm<256,64,true><<<dim3((Nn+63)/64, 1), 256, 0, stream>>>(g1, W2, h2b);
    k_att2<<<NB4, 256, 0, stream>>>(h2b, a_src2, a_dst2, asrc2, adst2);
    k_aggr2<<<NB4, 256, 0, stream>>>(h2b, asrc2, adst2, rowptr, csr, b2, g2);

    const int NCH = (Nn + POOL_CH - 1)/POOL_CH;   // 391
    k_pool<<<(NCH+3)/4, 256, 0, stream>>>(g2, batch, pooled, cnt);
    k_final<<<1, 1024, 0, stream>>>(pooled, cnt, fcW, fcb, out);
}

// Round 4
// 425.323 us; speedup vs baseline: 1.5940x; 1.1626x over previous
//
#include <hip/hip_runtime.h>
#include <hip/hip_bf16.h>

// GAT classifier: 2x GATConv + global_mean_pool + linear.
// N=50000, E=800000, IN=128, HID=64, HEADS=4, CLASSES=16, GRAPHS=64.
// R2: bf16 gathered features. R3: parallel device-wide scan.
// R4: MFMA bf16 GEMMs (LDS-free, pre-swizzled weights), g1 in bf16,
//     unroll-4 gather loops in aggr1/aggr2.

#define Nn 50000
#define Ed 800000
#define NEG 0.2f
#define SCAN_B 196   // ceil(50000/256)

typedef __attribute__((ext_vector_type(8))) short short8;
typedef __attribute__((ext_vector_type(4))) float f32x4;

__device__ __forceinline__ float lrelu(float x){ return fmaxf(x, NEG*x); }
__device__ __forceinline__ float bf2f(unsigned short u){ return __uint_as_float((unsigned)u << 16); }
__device__ __forceinline__ unsigned short f2bf(float f){
    __hip_bfloat16 b = __float2bfloat16(f);
    return *reinterpret_cast<unsigned short*>(&b);
}
__device__ __forceinline__ short f2bfs(float f){ return (short)f2bf(f); }

// ---------------- CSR build ----------------
__global__ void k_degree(const int* __restrict__ dst, int* __restrict__ deg){
    int e = blockIdx.x*256 + threadIdx.x;
    if (e < Ed) atomicAdd(&deg[dst[e]], 1);
}

__global__ __launch_bounds__(256) void k_partial(const int* __restrict__ deg, int* __restrict__ partial){
    __shared__ int red[256];
    int tid = threadIdx.x;
    int g = blockIdx.x*256 + tid;
    red[tid] = (g < Nn) ? deg[g] : 0;
    __syncthreads();
    for (int off = 128; off > 0; off >>= 1){
        if (tid < off) red[tid] += red[tid+off];
        __syncthreads();
    }
    if (tid == 0) partial[blockIdx.x] = red[0];
}

__global__ __launch_bounds__(256) void k_scanpartials(const int* __restrict__ partial,
                                                      int* __restrict__ psum, int* __restrict__ rowptr){
    __shared__ int s[256];
    int tid = threadIdx.x;
    int v = (tid < SCAN_B) ? partial[tid] : 0;
    s[tid] = v; __syncthreads();
    for (int off = 1; off < 256; off <<= 1){
        int t = (tid >= off) ? s[tid-off] : 0;
        __syncthreads();
        s[tid] += t;
        __syncthreads();
    }
    if (tid < SCAN_B) psum[tid] = s[tid] - v;   // exclusive
    if (tid == 255) rowptr[Nn] = s[255];
}

__global__ __launch_bounds__(256) void k_apply(const int* __restrict__ deg, const int* __restrict__ psum,
                                               int* __restrict__ rowptr, int* __restrict__ cursor){
    __shared__ int s[256];
    int tid = threadIdx.x;
    int g = blockIdx.x*256 + tid;
    int v = (g < Nn) ? deg[g] : 0;
    s[tid] = v; __syncthreads();
    for (int off = 1; off < 256; off <<= 1){
        int t = (tid >= off) ? s[tid-off] : 0;
        __syncthreads();
        s[tid] += t;
        __syncthreads();
    }
    if (g < Nn){
        int ex = s[tid] - v + psum[blockIdx.x];
        rowptr[g] = ex;
        cursor[g] = ex;
    }
}

__global__ void k_scatter(const int* __restrict__ src, const int* __restrict__ dst,
                          int* __restrict__ cursor, int* __restrict__ csr){
    int e = blockIdx.x*256 + threadIdx.x;
    if (e < Ed){
        int pos = atomicAdd(&cursor[dst[e]], 1);
        csr[pos] = src[e];
    }
}

// ---------------- weight pre-swizzle into MFMA B-fragment order ----------------
// W1s linear idx = ((nt*4+ks)*64 + lane)*8 + j  holds W1[ks*32+(lane>>4)*8+j][nt*16+(lane&15)]
// W2s linear idx = ((nt*8+ks)*64 + lane)*8 + j  holds W2[ks*32+(lane>>4)*8+j][nt*16+(lane&15)]
__global__ void k_prepw(const float* __restrict__ W1, const float* __restrict__ W2,
                        unsigned short* __restrict__ W1s, unsigned short* __restrict__ W2s){
    int t = blockIdx.x*256 + threadIdx.x;
    if (t < 32768){
        int j = t & 7, lane = (t>>3) & 63, ks = (t>>9) & 3, nt = t>>11;
        int k = ks*32 + (lane>>4)*8 + j;
        int n = nt*16 + (lane&15);
        W1s[t] = f2bf(W1[k*256 + n]);
    }
    if (t < 16384){
        int j = t & 7, lane = (t>>3) & 63, ks = (t>>9) & 7, nt = t>>12;
        int k = ks*32 + (lane>>4)*8 + j;
        int n = nt*16 + (lane&15);
        W2s[t] = f2bf(W2[k*64 + n]);
    }
}

// ---------------- MFMA GEMM 1: h1b[50000,256] = bf16(x @ W1) ----------------
// One wave per 16 rows; 16 n-tiles; K=128 in 4 steps of 32. No LDS.
__global__ __launch_bounds__(256) void k_gemm1(const float* __restrict__ x,
                                               const unsigned short* __restrict__ W1s,
                                               unsigned short* __restrict__ h1b){
    int wv = blockIdx.x*4 + (threadIdx.x>>6);
    int lane = threadIdx.x & 63;
    int m0 = wv*16;
    if (m0 >= Nn) return;
    int quad = lane >> 4, col = lane & 15;
    int mrow = m0 + col;
    f32x4 acc[16] = {};
    const float* ap0 = &x[(size_t)mrow*128 + quad*8];
    #pragma unroll
    for (int ks = 0; ks < 4; ks++){
        float4 a0 = *(const float4*)(ap0 + ks*32);
        float4 a1 = *(const float4*)(ap0 + ks*32 + 4);
        short8 af;
        af[0]=f2bfs(a0.x); af[1]=f2bfs(a0.y); af[2]=f2bfs(a0.z); af[3]=f2bfs(a0.w);
        af[4]=f2bfs(a1.x); af[5]=f2bfs(a1.y); af[6]=f2bfs(a1.z); af[7]=f2bfs(a1.w);
        #pragma unroll
        for (int nt = 0; nt < 16; nt++){
            short8 bf = *(const short8*)&W1s[(size_t)(nt*4+ks)*512 + lane*8];
            acc[nt] = __builtin_amdgcn_mfma_f32_16x16x32_bf16(af, bf, acc[nt], 0, 0, 0);
        }
    }
    unsigned short* outp = &h1b[(size_t)(m0 + quad*4)*256 + col];
    #pragma unroll
    for (int nt = 0; nt < 16; nt++)
        #pragma unroll
        for (int r = 0; r < 4; r++)
            outp[(size_t)r*256 + nt*16] = f2bf(acc[nt][r]);
}

// ---------------- MFMA GEMM 2: h2b[50000,64] = bf16(g1b @ W2) ----------------
__global__ __launch_bounds__(256) void k_gemm2(const unsigned short* __restrict__ g1b,
                                               const unsigned short* __restrict__ W2s,
                                               unsigned short* __restrict__ h2b){
    int wv = blockIdx.x*4 + (threadIdx.x>>6);
    int lane = threadIdx.x & 63;
    int m0 = wv*16;
    if (m0 >= Nn) return;
    int quad = lane >> 4, col = lane & 15;
    int mrow = m0 + col;
    f32x4 acc[4] = {};
    const unsigned short* ap0 = &g1b[(size_t)mrow*256 + quad*8];
    #pragma unroll
    for (int ks = 0; ks < 8; ks++){
        short8 af = *(const short8*)(ap0 + ks*32);
        #pragma unroll
        for (int nt = 0; nt < 4; nt++){
            short8 bf = *(const short8*)&W2s[(size_t)(nt*8+ks)*512 + lane*8];
            acc[nt] = __builtin_amdgcn_mfma_f32_16x16x32_bf16(af, bf, acc[nt], 0, 0, 0);
        }
    }
    unsigned short* outp = &h2b[(size_t)(m0 + quad*4)*64 + col];
    #pragma unroll
    for (int nt = 0; nt < 4; nt++)
        #pragma unroll
        for (int r = 0; r < 4; r++)
            outp[(size_t)r*64 + nt*16] = f2bf(acc[nt][r]);
}

// ---------------- attention coefficients (bf16 h input) ----------------
__global__ __launch_bounds__(256) void k_att1(const unsigned short* __restrict__ h1,
                                              const float* __restrict__ a_src, const float* __restrict__ a_dst,
                                              float* __restrict__ asrc, float* __restrict__ adst){
    int w = threadIdx.x >> 6, lane = threadIdx.x & 63;
    int n = blockIdx.x*4 + w; if (n >= Nn) return;
    const unsigned short* hr = &h1[(size_t)n*256];
    #pragma unroll
    for (int h = 0; h < 4; h++){
        float v = bf2f(hr[h*64 + lane]);
        float ps = v * a_src[h*64 + lane];
        float pd = v * a_dst[h*64 + lane];
        #pragma unroll
        for (int m = 32; m > 0; m >>= 1){ ps += __shfl_xor(ps, m); pd += __shfl_xor(pd, m); }
        if (lane == 0){ asrc[n*4+h] = ps; adst[n*4+h] = pd; }
    }
}

__global__ __launch_bounds__(256) void k_att2(const unsigned short* __restrict__ h2,
                                              const float* __restrict__ a_src, const float* __restrict__ a_dst,
                                              float* __restrict__ asrc, float* __restrict__ adst){
    int w = threadIdx.x >> 6, lane = threadIdx.x & 63;
    int n = blockIdx.x*4 + w; if (n >= Nn) return;
    float v = bf2f(h2[(size_t)n*64 + lane]);
    float ps = v * a_src[lane];
    float pd = v * a_dst[lane];
    #pragma unroll
    for (int m = 32; m > 0; m >>= 1){ ps += __shfl_xor(ps, m); pd += __shfl_xor(pd, m); }
    if (lane == 0){ asrc[n] = ps; adst[n] = pd; }
}

// ---------------- aggregation layer 1: one wave per dst node, unroll-4 ----------------
// Lane l owns dims [4l,4l+4) of the flattened 256 -> head = l>>4. Writes g1 in bf16.
__global__ __launch_bounds__(256) void k_aggr1(const unsigned short* __restrict__ h1,
                                               const float* __restrict__ asrc, const float* __restrict__ adst,
                                               const int* __restrict__ rowptr, const int* __restrict__ csr,
                                               const float* __restrict__ b1, unsigned short* __restrict__ g1){
    int w = threadIdx.x >> 6, lane = threadIdx.x & 63;
    int i = blockIdx.x*4 + w; if (i >= Nn) return;
    int hh = lane >> 4;
    float ad = adst[i*4 + hh];
    float as = asrc[i*4 + hh];
    float p = __expf(lrelu(as + ad));
    ushort4 hv = *(const ushort4*)&h1[(size_t)i*256 + 4*lane];
    float acc0 = p*bf2f(hv.x), acc1 = p*bf2f(hv.y), acc2 = p*bf2f(hv.z), acc3 = p*bf2f(hv.w);
    float ssum = p;
    int beg = rowptr[i], end = rowptr[i+1];
    int j = beg;
    for (; j + 3 < end; j += 4){
        int s0 = csr[j], s1 = csr[j+1], s2 = csr[j+2], s3 = csr[j+3];
        float a0 = asrc[s0*4 + hh];
        float a1 = asrc[s1*4 + hh];
        float a2 = asrc[s2*4 + hh];
        float a3 = asrc[s3*4 + hh];
        ushort4 v0 = *(const ushort4*)&h1[(size_t)s0*256 + 4*lane];
        ushort4 v1 = *(const ushort4*)&h1[(size_t)s1*256 + 4*lane];
        ushort4 v2 = *(const ushort4*)&h1[(size_t)s2*256 + 4*lane];
        ushort4 v3 = *(const ushort4*)&h1[(size_t)s3*256 + 4*lane];
        float q0 = __expf(lrelu(a0 + ad));
        float q1 = __expf(lrelu(a1 + ad));
        float q2 = __expf(lrelu(a2 + ad));
        float q3 = __expf(lrelu(a3 + ad));
        acc0 += q0*bf2f(v0.x) + q1*bf2f(v1.x) + q2*bf2f(v2.x) + q3*bf2f(v3.x);
        acc1 += q0*bf2f(v0.y) + q1*bf2f(v1.y) + q2*bf2f(v2.y) + q3*bf2f(v3.y);
        acc2 += q0*bf2f(v0.z) + q1*bf2f(v1.z) + q2*bf2f(v2.z) + q3*bf2f(v3.z);
        acc3 += q0*bf2f(v0.w) + q1*bf2f(v1.w) + q2*bf2f(v2.w) + q3*bf2f(v3.w);
        ssum += q0 + q1 + q2 + q3;
    }
    for (; j < end; j++){
        int s = csr[j];
        float a = asrc[s*4 + hh];
        ushort4 v = *(const ushort4*)&h1[(size_t)s*256 + 4*lane];
        float q = __expf(lrelu(a + ad));
        acc0 += q*bf2f(v.x); acc1 += q*bf2f(v.y);
        acc2 += q*bf2f(v.z); acc3 += q*bf2f(v.w);
        ssum += q;
    }
    float inv = 1.0f/(ssum + 1e-16f);
    float4 b4 = *(const float4*)&b1[4*lane];
    float o0 = acc0*inv + b4.x;
    float o1 = acc1*inv + b4.y;
    float o2 = acc2*inv + b4.z;
    float o3 = acc3*inv + b4.w;
    ushort4 o;
    o.x = f2bf(o0 > 0.f ? o0 : expm1f(o0));
    o.y = f2bf(o1 > 0.f ? o1 : expm1f(o1));
    o.z = f2bf(o2 > 0.f ? o2 : expm1f(o2));
    o.w = f2bf(o3 > 0.f ? o3 : expm1f(o3));
    *(ushort4*)&g1[(size_t)i*256 + 4*lane] = o;
}

// ---------------- aggregation layer 2: one wave per dst node, unroll-4 ----------------
__global__ __launch_bounds__(256) void k_aggr2(const unsigned short* __restrict__ h2,
                                               const float* __restrict__ asrc, const float* __restrict__ adst,
                                               const int* __restrict__ rowptr, const int* __restrict__ csr,
                                               const float* __restrict__ b2, float* __restrict__ g2){
    int w = threadIdx.x >> 6, lane = threadIdx.x & 63;
    int i = blockIdx.x*4 + w; if (i >= Nn) return;
    float ad = adst[i];
    float p = __expf(lrelu(asrc[i] + ad));
    float acc = p * bf2f(h2[(size_t)i*64 + lane]);
    float ss = p;
    int beg = rowptr[i], end = rowptr[i+1];
    int j = beg;
    for (; j + 3 < end; j += 4){
        int s0 = csr[j], s1 = csr[j+1], s2 = csr[j+2], s3 = csr[j+3];
        float a0 = asrc[s0], a1 = asrc[s1], a2 = asrc[s2], a3 = asrc[s3];
        unsigned short v0 = h2[(size_t)s0*64 + lane];
        unsigned short v1 = h2[(size_t)s1*64 + lane];
        unsigned short v2 = h2[(size_t)s2*64 + lane];
        unsigned short v3 = h2[(size_t)s3*64 + lane];
        float q0 = __expf(lrelu(a0 + ad));
        float q1 = __expf(lrelu(a1 + ad));
        float q2 = __expf(lrelu(a2 + ad));
        float q3 = __expf(lrelu(a3 + ad));
        acc += q0*bf2f(v0) + q1*bf2f(v1) + q2*bf2f(v2) + q3*bf2f(v3);
        ss += q0 + q1 + q2 + q3;
    }
    for (; j < end; j++){
        int s = csr[j];
        float q = __expf(lrelu(asrc[s] + ad));
        acc += q * bf2f(h2[(size_t)s*64 + lane]);
        ss += q;
    }
    g2[(size_t)i*64 + lane] = acc/(ss + 1e-16f) + b2[lane];
}

// ---------------- pooling + head ----------------
#define POOL_CH 128
__global__ __launch_bounds__(256) void k_pool(const float* __restrict__ g2, const int* __restrict__ batch,
                                              float* __restrict__ pooled, int* __restrict__ cnt){
    int w = threadIdx.x >> 6, lane = threadIdx.x & 63;
    int chunk = blockIdx.x*4 + w;
    int n0 = chunk*POOL_CH; if (n0 >= Nn) return;
    int n1 = min(n0 + POOL_CH, Nn);
    int cur = batch[n0];
    float acc = 0.f; int count = 0;
    for (int n = n0; n < n1; n++){
        int b = batch[n];
        if (b != cur){
            atomicAdd(&pooled[cur*64 + lane], acc);
            if (lane == 0) atomicAdd(&cnt[cur], count);
            acc = 0.f; count = 0; cur = b;
        }
        acc += g2[(size_t)n*64 + lane];
        count++;
    }
    atomicAdd(&pooled[cur*64 + lane], acc);
    if (lane == 0) atomicAdd(&cnt[cur], count);
}

__global__ void k_final(const float* __restrict__ pooled, const int* __restrict__ cnt,
                        const float* __restrict__ fcW, const float* __restrict__ fcb,
                        float* __restrict__ out){
    int t = threadIdx.x;       // 1024 threads: 64 graphs x 16 classes
    int g = t >> 4, c = t & 15;
    float inv = 1.0f / fmaxf((float)cnt[g], 1.0f);
    float acc = 0.f;
    for (int d = 0; d < 64; d++) acc += pooled[g*64 + d]*inv*fcW[d*16 + c];
    out[g*16 + c] = acc + fcb[c];
}

extern "C" void kernel_launch(void* const* d_in, const int* in_sizes, int n_in,
                              void* d_out, int out_size, void* d_ws, size_t ws_size,
                              hipStream_t stream) {
    const float* x      = (const float*)d_in[0];
    const int*   ei     = (const int*)d_in[1];   // [2][E]: ei = src, ei+Ed = dst
    const int*   batch  = (const int*)d_in[2];
    const float* W1     = (const float*)d_in[3];
    const float* a_src1 = (const float*)d_in[4];
    const float* a_dst1 = (const float*)d_in[5];
    const float* b1     = (const float*)d_in[6];
    const float* W2     = (const float*)d_in[7];
    const float* a_src2 = (const float*)d_in[8];
    const float* a_dst2 = (const float*)d_in[9];
    const float* b2     = (const float*)d_in[10];
    const float* fcW    = (const float*)d_in[11];
    const float* fcb    = (const float*)d_in[12];
    float* out = (float*)d_out;

    char* ws = (char*)d_ws;
    size_t off = 0;
    auto carve = [&](size_t bytes)->void*{
        void* p = ws + off;
        off += (bytes + 255) & ~(size_t)255;
        return p;
    };
    unsigned short* h1b = (unsigned short*)carve((size_t)Nn*256*2); // bf16(x@W1)
    unsigned short* g1b = (unsigned short*)carve((size_t)Nn*256*2); // bf16(elu(gat1))
    unsigned short* h2b = (unsigned short*)carve((size_t)Nn*64*2);  // bf16(g1@W2)
    float*          g2  = (float*)carve((size_t)Nn*64*4);           // gat2 out fp32
    float* asrc1  = (float*)carve((size_t)Nn*4*4);
    float* adst1  = (float*)carve((size_t)Nn*4*4);
    float* asrc2  = (float*)carve((size_t)Nn*4);
    float* adst2  = (float*)carve((size_t)Nn*4);
    int*   deg    = (int*)carve((size_t)Nn*4);
    int*   rowptr = (int*)carve((size_t)(Nn+1)*4);
    int*   cursor = (int*)carve((size_t)Nn*4);
    int*   csr    = (int*)carve((size_t)Ed*4);
    int*   partial= (int*)carve((size_t)SCAN_B*4);
    int*   psum   = (int*)carve((size_t)SCAN_B*4);
    unsigned short* W1s = (unsigned short*)carve(32768*2);
    unsigned short* W2s = (unsigned short*)carve(16384*2);
    float* pooled = (float*)carve(64*64*4);
    int*   cnt    = (int*)carve(64*4);

    hipMemsetAsync(deg, 0, (size_t)Nn*4, stream);
    hipMemsetAsync(pooled, 0, 64*64*4, stream);
    hipMemsetAsync(cnt, 0, 64*4, stream);

    const int EB = (Ed + 255)/256;
    const int NB4 = (Nn + 3)/4;
    const int GB = (Nn/16 + 3)/4 + 1;   // 782 blocks of 4 waves (16 rows each)

    k_degree<<<EB, 256, 0, stream>>>(ei + Ed, deg);
    k_partial<<<SCAN_B, 256, 0, stream>>>(deg, partial);
    k_scanpartials<<<1, 256, 0, stream>>>(partial, psum, rowptr);
    k_apply<<<SCAN_B, 256, 0, stream>>>(deg, psum, rowptr, cursor);
    k_scatter<<<EB, 256, 0, stream>>>(ei, ei + Ed, cursor, csr);
    k_prepw<<<128, 256, 0, stream>>>(W1, W2, W1s, W2s);

    k_gemm1<<<GB, 256, 0, stream>>>(x, W1s, h1b);
    k_att1<<<NB4, 256, 0, stream>>>(h1b, a_src1, a_dst1, asrc1, adst1);
    k_aggr1<<<NB4, 256, 0, stream>>>(h1b, asrc1, adst1, rowptr, csr, b1, g1b);

    k_gemm2<<<GB, 256, 0, stream>>>(g1b, W2s, h2b);
    k_att2<<<NB4, 256, 0, stream>>>(h2b, a_src2, a_dst2, asrc2, adst2);
    k_aggr2<<<NB4, 256, 0, stream>>>(h2b, asrc2, adst2, rowptr, csr, b2, g2);

    const int NCH = (Nn + POOL_CH - 1)/POOL_CH;   // 391
    k_pool<<<(NCH+3)/4, 256, 0, stream>>>(g2, batch, pooled, cnt);
    k_final<<<1, 1024, 0, stream>>>(pooled, cnt, fcW, fcb, out);
}